// Round 15
// baseline (195.528 us; speedup 1.0000x reference)
//
#include <hip/hip_runtime.h>

#define N_NODES 100000
#define N_EDGES 3200000
#define BATCH 16384
#define MAX_SLOTS 32768

// Single-pass nibble-packed degree histogram: 100K nodes x 4 bit = 50 KB LDS.
#define NW 12500       // words (8 nodes/word)
#define SLICES 256
#define EPS2 12500     // edges per slice
#define I4PS2 3125

// Buckets over slot space (128 slots / bucket); fixed arenas in bins.
#define NBUCK 256
#define BSH 7
#define BCAP 6144      // arena capacity/bucket; expected 3490 +/- 59 (+45 sigma)

// Workspace layout (byte offsets). ws_size = 256 MiB.
#define OFF_SLOT      0          // 100000 u32 (winners i+1; garbage elsewhere - cert-safe)
#define OFF_CURSOR    400000     // 256 ints (bucket arena cursors, seeded b*BCAP)
#define OFF_DINV      401024     // 100000 f32 (16B aligned)
#define OFF_NODELIST  801024     // 32768 ints (slot -> node, with duplicates)
#define OFF_SLOTSTART 932096     // 32769 ints
#define OFF_PARTIALS  1063232    // 256 x 12500 words = 12.8 MB nibble degree counts
#define OFF_WH        13863232   // bf16 w*dinv, 100000x64x2 B (16B aligned)
#define OFF_BINS      26663232   // 256 arenas x 6144 packed (slot_local<<17|src)
#define OFF_BINS2     32954688   // slot-sorted src ids, cap 1.2M
#define OFF_EMB       37754688   // bf16 32768x64 (16B aligned)

__device__ __forceinline__ unsigned bfr(float f) {   // fp32 -> bf16 bits, RNE
    unsigned u = __float_as_uint(f);
    return (u + 0x7FFFu + ((u >> 16) & 1u)) >> 16;
}
__device__ __forceinline__ float bfx(unsigned h) {   // low 16 bits -> fp32
    return __uint_as_float(h << 16);
}

// Certified needed-test: r=slot[d] valid iff (r-1)<32768 AND nodelist[r-1]==d.
__device__ __forceinline__ int cert(int d, const unsigned* __restrict__ slot,
                                    const int* __restrict__ nodelist) {
    unsigned r = slot[d];
    unsigned idx = r - 1u;
    if (idx < (unsigned)MAX_SLOTS && nodelist[idx] == d) return (int)idx;
    return -1;
}

// FUSED: flags (no-dedup slot assignment, 128 entries/block) + cursor seeding +
// nibble-packed degree histogram (ALL nodes, 50 KB LDS). slot/nodelist are only
// read by k_bscatter two launches later, so the fusion is dependency-free.
__global__ void k_hist(const int* __restrict__ dst, const int* __restrict__ pairs,
                       unsigned* __restrict__ slot, int* __restrict__ nodelist,
                       int* __restrict__ cursor, unsigned* __restrict__ partials) {
    __shared__ unsigned h[NW];
    int g = blockIdx.x;
    int tid = threadIdx.x;
    if (tid < 128) {
        int fi = g * 128 + tid;
        int n = pairs[fi];
        nodelist[fi] = n;
        slot[n] = (unsigned)(fi + 1);
    } else if (g == 0 && tid < 384) {
        int b = tid - 128;
        cursor[b] = b * BCAP;
    }
    for (int i = tid; i < NW; i += 512) h[i] = 0;
    __syncthreads();
    const int4* d4 = (const int4*)(dst + g * EPS2);
    for (int i = tid; i < I4PS2; i += 512) {
        int4 v = d4[i];
        atomicAdd(&h[v.x >> 3], 1u << ((v.x & 7) << 2));
        atomicAdd(&h[v.y >> 3], 1u << ((v.y & 7) << 2));
        atomicAdd(&h[v.z >> 3], 1u << ((v.z & 7) << 2));
        atomicAdd(&h[v.w >> 3], 1u << ((v.w & 7) << 2));
    }
    __syncthreads();
    unsigned* outp = partials + (unsigned)g * NW;
    for (int i = tid; i < NW; i += 512) outp[i] = h[i];
}

// Reduce nibble partials -> dinv; convert this block's 256 nodes' w rows to
// bf16 wh = w*dinv (uint4 stores). 391 blocks (no prefix half anymore).
__global__ void k_mid(const unsigned* __restrict__ partials, const float4* __restrict__ w4,
                      float* __restrict__ dinv, uint4* __restrict__ wh4) {
    __shared__ unsigned pA[256], pB[256], pC[256], pD[256];
    __shared__ float sdinv[256];
    int blk = blockIdx.x;
    int wi = threadIdx.x & 31, sg = threadIdx.x >> 5;    // word-in-block, slice-group
    int w = blk * 32 + wi;
    unsigned A = 0, B = 0, C = 0, D = 0;
    if (w < NW) {
        const unsigned* q = partials + w;
#pragma unroll
        for (int ch = 0; ch < 2; ++ch) {                 // 2 chunks x 16 slices
            unsigned x = 0, y = 0;
#pragma unroll
            for (int k = 0; k < 16; ++k) {
                unsigned v = q[(unsigned)(sg * 32 + ch * 16 + k) * NW];
                x += v & 0x0F0F0F0Fu;
                y += (v >> 4) & 0x0F0F0F0Fu;
            }
            A += x & 0x00FF00FFu;          // (n0, n4)
            B += (x >> 8) & 0x00FF00FFu;   // (n2, n6)
            C += y & 0x00FF00FFu;          // (n1, n5)
            D += (y >> 8) & 0x00FF00FFu;   // (n3, n7)
        }
    }
    pA[threadIdx.x] = A; pB[threadIdx.x] = B; pC[threadIdx.x] = C; pD[threadIdx.x] = D;
    __syncthreads();
    if (threadIdx.x < 32 && w < NW) {
        unsigned sA = 0, sB = 0, sC = 0, sD = 0;
#pragma unroll
        for (int k = 0; k < 8; ++k) {
            sA += pA[k * 32 + wi]; sB += pB[k * 32 + wi];
            sC += pC[k * 32 + wi]; sD += pD[k * 32 + wi];
        }
        float4 d0, d1;
        d0.x = rsqrtf((float)(sA & 0xFFFFu) + 1.0f);
        d0.y = rsqrtf((float)(sC & 0xFFFFu) + 1.0f);
        d0.z = rsqrtf((float)(sB & 0xFFFFu) + 1.0f);
        d0.w = rsqrtf((float)(sD & 0xFFFFu) + 1.0f);
        d1.x = rsqrtf((float)(sA >> 16) + 1.0f);
        d1.y = rsqrtf((float)(sC >> 16) + 1.0f);
        d1.z = rsqrtf((float)(sB >> 16) + 1.0f);
        d1.w = rsqrtf((float)(sD >> 16) + 1.0f);
        ((float4*)dinv)[w * 2] = d0;
        ((float4*)dinv)[w * 2 + 1] = d1;
        int lb = wi * 8;
        sdinv[lb + 0] = d0.x; sdinv[lb + 1] = d0.y; sdinv[lb + 2] = d0.z; sdinv[lb + 3] = d0.w;
        sdinv[lb + 4] = d1.x; sdinv[lb + 5] = d1.y; sdinv[lb + 6] = d1.z; sdinv[lb + 7] = d1.w;
    }
    __syncthreads();
#pragma unroll
    for (int it = 0; it < 8; ++it) {
        int k = blk * 2048 + it * 256 + threadIdx.x;   // uint4 index (8 dims); node = k>>3
        if (k < N_NODES * 8) {
            float4 va = w4[k * 2];
            float4 vb = w4[k * 2 + 1];
            float d = sdinv[(k >> 3) - blk * 256];
            uint4 o;
            o.x = bfr(va.x * d) | (bfr(va.y * d) << 16);
            o.y = bfr(va.z * d) | (bfr(va.w * d) << 16);
            o.z = bfr(vb.x * d) | (bfr(vb.y * d) << 16);
            o.w = bfr(vb.z * d) | (bfr(vb.w * d) << 16);
            wh4[k] = o;
        }
    }
}

// Two-pass arena scatter: pass 1 counts certified edges per bucket in LDS; one
// device atomic per (block, nonempty bucket) grabs an arena range (<=65K total);
// pass 2 re-reads the block's own 100 KB slice (L2-hot) and writes entries.
__global__ void k_bscatter(const int* __restrict__ src, const int* __restrict__ dst,
                           const unsigned* __restrict__ slot, const int* __restrict__ nodelist,
                           int* __restrict__ cursor, int* __restrict__ bins) {
    __shared__ int ecnt[NBUCK];
    int g = blockIdx.x;
    int tid = threadIdx.x;
    if (tid < NBUCK) ecnt[tid] = 0;
    __syncthreads();
    const int4* d4 = (const int4*)(dst + g * EPS2);
    const int4* s4 = (const int4*)(src + g * EPS2);
    for (int i = tid; i < I4PS2; i += 512) {
        int4 d = d4[i];
        int t;
        t = cert(d.x, slot, nodelist); if (t >= 0) atomicAdd(&ecnt[t >> BSH], 1);
        t = cert(d.y, slot, nodelist); if (t >= 0) atomicAdd(&ecnt[t >> BSH], 1);
        t = cert(d.z, slot, nodelist); if (t >= 0) atomicAdd(&ecnt[t >> BSH], 1);
        t = cert(d.w, slot, nodelist); if (t >= 0) atomicAdd(&ecnt[t >> BSH], 1);
    }
    __syncthreads();
    if (tid < NBUCK) {
        int c = ecnt[tid];
        ecnt[tid] = (c > 0) ? atomicAdd(&cursor[tid], c) : 0;   // becomes write cursor
    }
    __syncthreads();
    for (int i = tid; i < I4PS2; i += 512) {
        int4 d = d4[i];
        int4 s = s4[i];
        int t;
        t = cert(d.x, slot, nodelist);
        if (t >= 0) { int pos = atomicAdd(&ecnt[t >> BSH], 1); bins[pos] = ((t & 127) << 17) | s.x; }
        t = cert(d.y, slot, nodelist);
        if (t >= 0) { int pos = atomicAdd(&ecnt[t >> BSH], 1); bins[pos] = ((t & 127) << 17) | s.y; }
        t = cert(d.z, slot, nodelist);
        if (t >= 0) { int pos = atomicAdd(&ecnt[t >> BSH], 1); bins[pos] = ((t & 127) << 17) | s.z; }
        t = cert(d.w, slot, nodelist);
        if (t >= 0) { int pos = atomicAdd(&ecnt[t >> BSH], 1); bins[pos] = ((t & 127) << 17) | s.w; }
    }
}

// Per-bucket counting sort (arena -> compact slot-sorted bins2 + slotstart).
// Bucket sizes derived from post-scatter cursors; inline cross-bucket scan.
__global__ void k_bsort(const int* __restrict__ cursor, const int* __restrict__ bins,
                        int* __restrict__ slotstart, int* __restrict__ bins2) {
    __shared__ int tb[NBUCK], vv[NBUCK];
    __shared__ int lc[128], st[128];
    int b = blockIdx.x;
    int tid = threadIdx.x;
    { int c = cursor[tid] - tid * BCAP; vv[tid] = c; tb[tid] = c; }
    __syncthreads();
    for (int off = 1; off < NBUCK; off <<= 1) {
        int x = (tid >= off) ? tb[tid - off] : 0;
        __syncthreads();
        tb[tid] += x;
        __syncthreads();
    }
    int obeg = tb[b] - vv[b];     // output base in bins2
    int ibeg = b * BCAP;          // arena base in bins
    int cnt = vv[b];
    if (tid < 128) lc[tid] = 0;
    __syncthreads();
    for (int j = tid; j < cnt; j += 256)
        atomicAdd(&lc[(bins[ibeg + j] >> 17) & 127], 1);
    __syncthreads();
    if (tid < 128) st[tid] = lc[tid];
    __syncthreads();
    for (int off = 1; off < 128; off <<= 1) {
        int v = (tid < 128 && tid >= off) ? st[tid - off] : 0;
        __syncthreads();
        if (tid < 128) st[tid] += v;
        __syncthreads();
    }
    if (tid < 128) {
        int s0 = obeg + st[tid] - lc[tid];
        slotstart[(b << 7) + tid] = s0;
        lc[tid] = s0;
    }
    if (b == NBUCK - 1 && tid == 0) slotstart[MAX_SLOTS] = tb[NBUCK - 1];
    __syncthreads();
    for (int j = tid; j < cnt; j += 256) {
        int e = bins[ibeg + j];
        int pos = atomicAdd(&lc[(e >> 17) & 127], 1);
        bins2[pos] = e & 0x1FFFF;
    }
}

// One wave per slot (all 32768; loser/duplicate slots have empty bins), 8 rows
// per instruction: lane = (rg = lane>>3) x (dp = lane&7), uint4 loads.
__global__ void k_gather(const int* __restrict__ nodelist, const int* __restrict__ slotstart,
                         const int* __restrict__ bins2, const uint4* __restrict__ wh4,
                         const float* __restrict__ dinv, const float4* __restrict__ bias4,
                         uint4* __restrict__ emb4) {
    int s = (blockIdx.x * blockDim.x + threadIdx.x) >> 6;
    int lane = threadIdx.x & 63;
    int rg = lane >> 3, dp = lane & 7;
    int beg = slotstart[s], end = slotstart[s + 1];
    float a0 = 0.f, a1 = 0.f, a2 = 0.f, a3 = 0.f, a4 = 0.f, a5 = 0.f, a6 = 0.f, a7 = 0.f;
    int j = beg;
    for (; j + 16 <= end; j += 16) {
        int e0 = bins2[j + rg];
        int e1 = bins2[j + 8 + rg];
        uint4 oa = wh4[(e0 << 3) + dp];
        uint4 ob = wh4[(e1 << 3) + dp];
        a0 += bfx(oa.x) + bfx(ob.x);
        a1 += bfx(oa.x >> 16) + bfx(ob.x >> 16);
        a2 += bfx(oa.y) + bfx(ob.y);
        a3 += bfx(oa.y >> 16) + bfx(ob.y >> 16);
        a4 += bfx(oa.z) + bfx(ob.z);
        a5 += bfx(oa.z >> 16) + bfx(ob.z >> 16);
        a6 += bfx(oa.w) + bfx(ob.w);
        a7 += bfx(oa.w >> 16) + bfx(ob.w >> 16);
    }
    for (; j < end; j += 8) {
        if (rg < end - j) {
            int e0 = bins2[j + rg];
            uint4 oa = wh4[(e0 << 3) + dp];
            a0 += bfx(oa.x); a1 += bfx(oa.x >> 16);
            a2 += bfx(oa.y); a3 += bfx(oa.y >> 16);
            a4 += bfx(oa.z); a5 += bfx(oa.z >> 16);
            a6 += bfx(oa.w); a7 += bfx(oa.w >> 16);
        }
    }
#pragma unroll
    for (int m = 8; m <= 32; m <<= 1) {
        a0 += __shfl_xor(a0, m, 64); a1 += __shfl_xor(a1, m, 64);
        a2 += __shfl_xor(a2, m, 64); a3 += __shfl_xor(a3, m, 64);
        a4 += __shfl_xor(a4, m, 64); a5 += __shfl_xor(a5, m, 64);
        a6 += __shfl_xor(a6, m, 64); a7 += __shfl_xor(a7, m, 64);
    }
    if (rg == 0) {
        int n = nodelist[s];
        float dn = dinv[n];
        uint4 u = wh4[(n << 3) + dp];
        float4 b0 = bias4[dp * 2], b1 = bias4[dp * 2 + 1];
        float r0 = (a0 + bfx(u.x)) * dn + b0.x;
        float r1 = (a1 + bfx(u.x >> 16)) * dn + b0.y;
        float r2 = (a2 + bfx(u.y)) * dn + b0.z;
        float r3 = (a3 + bfx(u.y >> 16)) * dn + b0.w;
        float r4 = (a4 + bfx(u.z)) * dn + b1.x;
        float r5 = (a5 + bfx(u.z >> 16)) * dn + b1.y;
        float r6 = (a6 + bfx(u.w)) * dn + b1.z;
        float r7 = (a7 + bfx(u.w >> 16)) * dn + b1.w;
        uint4 o;
        o.x = bfr(r0) | (bfr(r1) << 16);
        o.y = bfr(r2) | (bfr(r3) << 16);
        o.z = bfr(r4) | (bfr(r5) << 16);
        o.w = bfr(r6) | (bfr(r7) << 16);
        emb4[(s << 3) + dp] = o;
    }
}

// Four pairs per wave (16 lanes each), uint2 loads (4 dims/lane).
__global__ void k_final(const int* __restrict__ pairs, const unsigned* __restrict__ slot,
                        const uint2* __restrict__ emb2, const float* __restrict__ lw,
                        const float* __restrict__ lb, float* __restrict__ out) {
    int p = (blockIdx.x * blockDim.x + threadIdx.x) >> 4;
    int li = threadIdx.x & 15;
    if (p >= BATCH) return;
    int a = pairs[p * 2], b = pairs[p * 2 + 1];
    int sa = (int)slot[a] - 1;
    int sb = (int)slot[b] - 1;
    uint2 ua = emb2[(sa << 4) + li];
    uint2 ub = emb2[(sb << 4) + li];
    float prod = bfx(ua.x) * bfx(ub.x) + bfx(ua.x >> 16) * bfx(ub.x >> 16)
               + bfx(ua.y) * bfx(ub.y) + bfx(ua.y >> 16) * bfx(ub.y >> 16);
#pragma unroll
    for (int m = 1; m <= 8; m <<= 1) prod += __shfl_xor(prod, m, 64);
    if (li == 0) out[p] = lw[a] + lw[b] + lb[0] + prod;
}

extern "C" void kernel_launch(void* const* d_in, const int* in_sizes, int n_in,
                              void* d_out, int out_size, void* d_ws, size_t ws_size,
                              hipStream_t stream) {
    const float* gcn_weight    = (const float*)d_in[0];
    const float* gcn_bias      = (const float*)d_in[1];
    const float* linear_weight = (const float*)d_in[2];
    const float* linear_bias   = (const float*)d_in[3];
    const int*   edge_index    = (const int*)d_in[4];
    const int*   pairs         = (const int*)d_in[5];
    float* out = (float*)d_out;

    char* ws = (char*)d_ws;
    unsigned* slot      = (unsigned*)(ws + OFF_SLOT);
    int*      cursor    = (int*)     (ws + OFF_CURSOR);
    float*    dinv      = (float*)   (ws + OFF_DINV);
    int*      nodelist  = (int*)     (ws + OFF_NODELIST);
    int*      slotstart = (int*)     (ws + OFF_SLOTSTART);
    unsigned* partials  = (unsigned*)(ws + OFF_PARTIALS);
    uint4*    wh4       = (uint4*)   (ws + OFF_WH);
    int*      bins      = (int*)     (ws + OFF_BINS);
    int*      bins2     = (int*)     (ws + OFF_BINS2);
    uint4*    emb4      = (uint4*)   (ws + OFF_EMB);
    uint2*    emb2      = (uint2*)   (ws + OFF_EMB);

    const int* src_arr = edge_index;
    const int* dst_arr = edge_index + N_EDGES;

    k_hist<<<SLICES, 512, 0, stream>>>(dst_arr, pairs, slot, nodelist, cursor, partials);
    k_mid<<<391, 256, 0, stream>>>(partials, (const float4*)gcn_weight, dinv, wh4);
    k_bscatter<<<SLICES, 512, 0, stream>>>(src_arr, dst_arr, slot, nodelist, cursor, bins);
    k_bsort<<<NBUCK, 256, 0, stream>>>(cursor, bins, slotstart, bins2);
    k_gather<<<MAX_SLOTS / 4, 256, 0, stream>>>(nodelist, slotstart, bins2, wh4,
                                                dinv, (const float4*)gcn_bias, emb4);
    k_final<<<1024, 256, 0, stream>>>(pairs, slot, emb2, linear_weight, linear_bias, out);
}